// Round 1
// baseline (1079.621 us; speedup 1.0000x reference)
//
#include <hip/hip_runtime.h>
#include <math.h>
#include <stdint.h>

#define T_DATA 20000
#define E_NO   2000
#define I_NO   500
#define SUB    16
#define TNO    200
#define NBLK   313   // ceil(20000/64)

// ---------------- workspace layout (float offsets) ----------------
// 0       ek[3200]   (s*200+t)
// 3200    ik[3200]
// 6400    hist[200]
// 6600    ewsub[16]
// 6616    we[2000]
// 8616    wi[500]
// 16384   synE[20000*16]
// 336384  synI[20000*16]
// 656384  negd[20000]
// 676384  me[2000] (int)
// 678384  mi[500]  (int)
// 678884  cmask[16](int)

// ---------------------------------------------------------------------------
// K1: per-subunit kernels, hist kernel, synapse->subunit maps, tree masks.
// Also writes out_filters rows (e_kern 0..15, i_kern 16..31, hist 32).
// ---------------------------------------------------------------------------
__global__ __launch_bounds__(256) void k_prep(
    const float* __restrict__ Ce, const float* __restrict__ Ci,
    const float* __restrict__ cosb,
    const float* __restrict__ TauE, const float* __restrict__ TauI,
    const float* __restrict__ We,  const float* __restrict__ Wi,
    const float* __restrict__ De,  const float* __restrict__ Di,
    const float* __restrict__ Wsub, const float* __restrict__ Whist,
    const int* __restrict__ Cden,
    float* __restrict__ ws_ek, float* __restrict__ ws_ik,
    float* __restrict__ ws_hist, float* __restrict__ ws_ewsub,
    float* __restrict__ ws_we, float* __restrict__ ws_wi,
    int* __restrict__ ws_me, int* __restrict__ ws_mi, int* __restrict__ ws_cmask,
    float* __restrict__ out_filt) {
  int tid = threadIdx.x;
  // alpha kernels
  for (int idx = tid; idx < SUB * TNO; idx += 256) {
    int s = idx / TNO;
    float tf = (float)(idx % TNO);
    float te  = fmaxf(tf - expf(De[s]), 0.f);
    float tte = te / expf(TauE[s]);
    float ekv = tte * expf(-tte) * expf(We[s]);
    float ti_ = fmaxf(tf - expf(Di[s]), 0.f);
    float tti = ti_ / expf(TauI[s]);
    float ikv = -(tti * expf(-tti) * expf(Wi[s]));
    ws_ek[idx] = ekv;
    ws_ik[idx] = ikv;
    out_filt[idx] = ekv;            // rows 0..15
    out_filt[3200 + idx] = ikv;     // rows 16..31
  }
  // hist kernel
  for (int t = tid; t < TNO; t += 256) {
    float h = 0.f;
    for (int b = 0; b < 16; ++b) h = fmaf(Whist[b], cosb[b * TNO + t], h);
    ws_hist[t] = h;
    out_filt[6400 + t] = h;         // row 32 (unflipped)
  }
  // synapse->subunit maps (columns are one-hot in the reference setup)
  for (int e = tid; e < E_NO; e += 256) {
    int m = 0; float w = 0.f;
    for (int s = 0; s < SUB; ++s) {
      float v = Ce[s * E_NO + e];
      if (w == 0.f && v != 0.f) { m = s; w = v; }
    }
    ws_me[e] = m; ws_we[e] = w;
  }
  for (int e = tid; e < I_NO; e += 256) {
    int m = 0; float w = 0.f;
    for (int s = 0; s < SUB; ++s) {
      float v = Ci[s * I_NO + e];
      if (w == 0.f && v != 0.f) { m = s; w = v; }
    }
    ws_mi[e] = m; ws_wi[e] = w;
  }
  if (tid < SUB) {
    ws_ewsub[tid] = expf(Wsub[tid]);
    int msk = 0;
    for (int j = 0; j < SUB; ++j)
      if (Cden[tid * SUB + j] == 1) msk |= (1 << j);
    ws_cmask[tid] = msk;
  }
}

// ---------------------------------------------------------------------------
// K2: synapse aggregation S_e@C_e^T, S_i@C_i^T -> synE/synI [20000][16].
// Deterministic: per-lane LDS bins + fixed-order sequential reduction.
// ---------------------------------------------------------------------------
__global__ __launch_bounds__(256) void k_agg(
    const float4* __restrict__ Se4, const float4* __restrict__ Si4,
    const int* __restrict__ me, const float* __restrict__ we,
    const int* __restrict__ mi, const float* __restrict__ wi,
    float* __restrict__ synE, float* __restrict__ synI) {
  __shared__ float bins[4][64][33];   // [wave][lane][32 bins], stride 33 (2-way = free)
  int tid = threadIdx.x, wid = tid >> 6, l = tid & 63;
  int gw = blockIdx.x * 4 + wid;      // 0..4999
  for (int r = 0; r < 4; ++r) {
    int t = gw * 4 + r;               // 0..19999
#pragma unroll
    for (int s = 0; s < 32; ++s) bins[wid][l][s] = 0.f;
    // E synapses: 500 float4 per row
    for (int i = 0; i < 8; ++i) {
      int idx = i * 64 + l;
      if (idx < 500) {
        float4 v = Se4[(size_t)t * 500 + idx];
        int e0 = idx * 4;
        if (v.x != 0.f) bins[wid][l][me[e0 + 0]] += v.x * we[e0 + 0];
        if (v.y != 0.f) bins[wid][l][me[e0 + 1]] += v.y * we[e0 + 1];
        if (v.z != 0.f) bins[wid][l][me[e0 + 2]] += v.z * we[e0 + 2];
        if (v.w != 0.f) bins[wid][l][me[e0 + 3]] += v.w * we[e0 + 3];
      }
    }
    // I synapses: 125 float4 per row -> bins 16..31
    for (int i = 0; i < 2; ++i) {
      int idx = i * 64 + l;
      if (idx < 125) {
        float4 v = Si4[(size_t)t * 125 + idx];
        int e0 = idx * 4;
        if (v.x != 0.f) bins[wid][l][16 + mi[e0 + 0]] += v.x * wi[e0 + 0];
        if (v.y != 0.f) bins[wid][l][16 + mi[e0 + 1]] += v.y * wi[e0 + 1];
        if (v.z != 0.f) bins[wid][l][16 + mi[e0 + 2]] += v.z * wi[e0 + 2];
        if (v.w != 0.f) bins[wid][l][16 + mi[e0 + 3]] += v.w * wi[e0 + 3];
      }
    }
    __syncthreads();
    if (l < 32) {
      float a = 0.f;
      for (int k = 0; k < 64; ++k) a += bins[wid][k][l];   // fixed order
      if (l < 16) synE[(size_t)t * 16 + l] = a;
      else        synI[(size_t)t * 16 + (l - 16)] = a;
    }
    __syncthreads();
  }
}

// ---------------------------------------------------------------------------
// K3: causal filtering (strictly causal, 1-step delay) + dendritic tree
// -> negd[t] = -drive[t].
// ---------------------------------------------------------------------------
__global__ __launch_bounds__(64) void k_filt(
    const float* __restrict__ synE, const float* __restrict__ synI,
    const float* __restrict__ ek_ws, const float* __restrict__ ik_ws,
    const float* __restrict__ theta, const float* __restrict__ ewsub,
    const int* __restrict__ cmask,
    float* __restrict__ negd) {
  __shared__ float sE[264 * 17];     // rows t0-200 .. t0+63, stride 17 (conflict-free)
  __shared__ float sI[264 * 17];
  __shared__ float ekl[TNO * 16];    // [j][s]
  __shared__ float ikl[TNO * 16];
  int l = threadIdx.x;
  int t0 = blockIdx.x * 64;
  for (int idx = l; idx < 264 * 16; idx += 64) {
    int row = idx >> 4, s = idx & 15;
    int g = t0 - 200 + row;
    bool ok = (g >= 0) && (g < T_DATA);
    sE[row * 17 + s] = ok ? synE[(size_t)g * 16 + s] : 0.f;
    sI[row * 17 + s] = ok ? synI[(size_t)g * 16 + s] : 0.f;
  }
  for (int idx = l; idx < SUB * TNO; idx += 64) {
    int s = idx / TNO, j = idx % TNO;
    ekl[j * 16 + s] = ek_ws[idx];
    ikl[j * 16 + s] = ik_ws[idx];
  }
  __syncthreads();
  int t = t0 + l;
  float acc[16];
#pragma unroll
  for (int s = 0; s < 16; ++s) acc[s] = 0.f;
  // out[t] = sum_j kern[j] * syn[t-1-j]; LDS row (t-1-j) - (t0-200) = l + 199 - j
  for (int j = 0; j < TNO; ++j) {
    int base = (l + 199 - j) * 17;
    int kb = j * 16;
#pragma unroll
    for (int s = 0; s < 16; ++s)
      acc[s] = fmaf(ekl[kb + s], sE[base + s], fmaf(ikl[kb + s], sI[base + s], acc[s]));
  }
  // dendritic tree, leaf-to-root (static 16x16 unroll keeps val[] in registers)
  float th[16], ew[16]; int cm[16];
#pragma unroll
  for (int s = 0; s < 16; ++s) { th[s] = theta[s]; ew[s] = ewsub[s]; cm[s] = cmask[s]; }
  float val[16];
#pragma unroll
  for (int s = 0; s < 16; ++s) val[s] = 0.f;
#pragma unroll
  for (int sidx = 15; sidx >= 1; --sidx) {
    float sum = acc[sidx] + th[sidx];
#pragma unroll
    for (int j = 0; j < 16; ++j)
      if ((cm[sidx] >> j) & 1) sum += val[j] * ew[j];
    val[sidx] = tanhf(sum);
  }
  float drive = acc[0] + th[0];
#pragma unroll
  for (int j = 0; j < 16; ++j)
    if ((cm[0] >> j) & 1) drive += val[j] * ew[j];
  if (t < T_DATA) negd[t] = -drive;
}

// ---------------------------------------------------------------------------
// K4: sequential spike scan. 1 workgroup, 4 waves.
// wave0: lane l owns x[t0+l]; per-step ballot broadcasts the decision bit.
//   spike at t0+i adds h[l-i-1] to lane l (hpad zero-prefix masks l<=i).
//   prev-block spikes: 64-tap conv from bitmask (m in [1,127]).
// waves1-3: deep feedback m>=65 for block n+1 from spikes <= block n-1,
//   computed during block n (double-buffered, 1 barrier/block).
// ---------------------------------------------------------------------------
__global__ __launch_bounds__(256) void k_scan(
    const float* __restrict__ hist, const float* __restrict__ negd,
    float* __restrict__ out_spk) {
  __shared__ float hpad[328];        // [0..63]=0, [64..263]=h[0..199], [264..327]=0
  __shared__ float spkf[512];        // spike ring (float 0/1)
  __shared__ float deepb[2][3][64];  // parity double-buffered deep partials
  int tid = threadIdx.x, wid = tid >> 6, l = tid & 63;
  for (int i = tid; i < 328; i += 256) hpad[i] = (i >= 64 && i < 264) ? hist[i - 64] : 0.f;
  for (int i = tid; i < 512; i += 256) spkf[i] = 0.f;
  for (int i = tid; i < 2 * 3 * 64; i += 256) (&deepb[0][0][0])[i] = 0.f;
  __syncthreads();

  unsigned long long mask_prev = 0ull;
  float ndv = (wid == 0) ? negd[l] : 0.f;
  int k0 = (wid == 1) ? 0 : (wid == 2) ? 46 : 91;
  int k1 = (wid == 1) ? 46 : (wid == 2) ? 91 : 136;

  for (int n = 0; n < NBLK; ++n) {
    int t0 = n * 64;
    if (wid == 0) {
      // prefetch next block's -drive (consumed next iteration)
      int tn = t0 + 64 + l;
      float ndnext = (tn < T_DATA) ? negd[tn] : INFINITY;
      int par = n & 1;
      float X = deepb[par][0][l] + deepb[par][1][l] + deepb[par][2][l];
      // previous-block spikes: m = 64+l-i in [1,127]
      {
        float a0 = 0.f, a1 = 0.f, a2 = 0.f, a3 = 0.f;
#pragma unroll
        for (int i = 0; i < 64; i += 4) {
          a0 = fmaf((float)((mask_prev >> (i + 0)) & 1ull), hpad[127 + l - (i + 0)], a0);
          a1 = fmaf((float)((mask_prev >> (i + 1)) & 1ull), hpad[127 + l - (i + 1)], a1);
          a2 = fmaf((float)((mask_prev >> (i + 2)) & 1ull), hpad[127 + l - (i + 2)], a2);
          a3 = fmaf((float)((mask_prev >> (i + 3)) & 1ull), hpad[127 + l - (i + 3)], a3);
        }
        X += (a0 + a1) + (a2 + a3);
      }
      // sequential chain over 64 steps
      unsigned long long msk = 0ull;
#pragma unroll
      for (int i = 0; i < 64; ++i) {
        unsigned long long bm = __ballot(X > ndv);       // bit i = step-i decision
        float spf = (float)((bm >> i) & 1ull);
        X = fmaf(spf, hpad[63 + l - i], X);              // h[l-i-1]; zero for l<=i
        msk |= (bm & (1ull << i));
      }
      // publish
      float myspk = (float)((msk >> l) & 1ull);
      int t = t0 + l;
      if (t < T_DATA) out_spk[t] = myspk;
      spkf[t & 511] = myspk;
      mask_prev = msk;
      ndv = ndnext;
    } else {
      // deep feedback for block n+1: spikes u = t0-1-k (k in [0,136)), m = 65+l+k
      float acc = 0.f;
      for (int k = k0; k < k1; ++k) {
        float sp = spkf[(t0 - 1 - k) & 511];
        acc = fmaf(sp, hpad[128 + l + k], acc);          // zero-clamped for m > 200
      }
      deepb[(n + 1) & 1][wid - 1][l] = acc;
    }
    __syncthreads();
  }
}

// ---------------------------------------------------------------------------
extern "C" void kernel_launch(void* const* d_in, const int* in_sizes, int n_in,
                              void* d_out, int out_size, void* d_ws, size_t ws_size,
                              hipStream_t stream) {
  const float* S_e      = (const float*)d_in[0];
  const float* S_i      = (const float*)d_in[1];
  const int*   C_den    = (const int*)d_in[2];
  const float* C_syn_e  = (const float*)d_in[3];
  const float* C_syn_i  = (const float*)d_in[4];
  const float* cos_b    = (const float*)d_in[5];
  const float* Tau_e    = (const float*)d_in[6];
  const float* Tau_i    = (const float*)d_in[7];
  const float* W_e      = (const float*)d_in[8];
  const float* W_i      = (const float*)d_in[9];
  const float* D_e      = (const float*)d_in[10];
  const float* D_i      = (const float*)d_in[11];
  const float* W_sub    = (const float*)d_in[12];
  const float* W_hist   = (const float*)d_in[13];
  const float* Theta    = (const float*)d_in[14];
  float* out = (float*)d_out;

  float* wsf      = (float*)d_ws;
  float* ws_ek    = wsf;
  float* ws_ik    = wsf + 3200;
  float* ws_hist  = wsf + 6400;
  float* ws_ewsub = wsf + 6600;
  float* ws_we    = wsf + 6616;
  float* ws_wi    = wsf + 8616;
  float* synE     = wsf + 16384;
  float* synI     = wsf + 336384;
  float* negd     = wsf + 656384;
  int*   ws_me    = (int*)(wsf + 676384);
  int*   ws_mi    = (int*)(wsf + 678384);
  int*   ws_cmask = (int*)(wsf + 678884);

  k_prep<<<dim3(1), dim3(256), 0, stream>>>(
      C_syn_e, C_syn_i, cos_b, Tau_e, Tau_i, W_e, W_i, D_e, D_i, W_sub, W_hist,
      C_den, ws_ek, ws_ik, ws_hist, ws_ewsub, ws_we, ws_wi, ws_me, ws_mi,
      ws_cmask, out + T_DATA);

  k_agg<<<dim3(1250), dim3(256), 0, stream>>>(
      (const float4*)S_e, (const float4*)S_i, ws_me, ws_we, ws_mi, ws_wi,
      synE, synI);

  k_filt<<<dim3(NBLK), dim3(64), 0, stream>>>(
      synE, synI, ws_ek, ws_ik, Theta, ws_ewsub, ws_cmask, negd);

  k_scan<<<dim3(1), dim3(256), 0, stream>>>(ws_hist, negd, out);
}

// Round 2
// 940.993 us; speedup vs baseline: 1.1473x; 1.1473x over previous
//
#include <hip/hip_runtime.h>
#include <math.h>
#include <stdint.h>

#define T_DATA 20000
#define E_NO   2000
#define I_NO   500
#define SUB    16
#define TNO    200
#define NBLK   313   // ceil(20000/64)

// ---------------- workspace layout (float offsets) ----------------
// 0       ek[3200]   (s*200+t)
// 3200    ik[3200]
// 6400    hist[200]
// 6600    ewsub[16]
// 6616    we[2000]
// 8616    wi[500]
// 16384   synE[20000*16]
// 336384  synI[20000*16]
// 656384  negd[20000]
// 676384  me[2000] (int)
// 678384  mi[500]  (int)
// 678884  cmask[16](int)

// ---------------------------------------------------------------------------
// K1: per-subunit kernels, hist kernel, synapse->subunit maps, tree masks.
// Also writes out_filters rows (e_kern 0..15, i_kern 16..31, hist 32).
// ---------------------------------------------------------------------------
__global__ __launch_bounds__(256) void k_prep(
    const float* __restrict__ Ce, const float* __restrict__ Ci,
    const float* __restrict__ cosb,
    const float* __restrict__ TauE, const float* __restrict__ TauI,
    const float* __restrict__ We,  const float* __restrict__ Wi,
    const float* __restrict__ De,  const float* __restrict__ Di,
    const float* __restrict__ Wsub, const float* __restrict__ Whist,
    const int* __restrict__ Cden,
    float* __restrict__ ws_ek, float* __restrict__ ws_ik,
    float* __restrict__ ws_hist, float* __restrict__ ws_ewsub,
    float* __restrict__ ws_we, float* __restrict__ ws_wi,
    int* __restrict__ ws_me, int* __restrict__ ws_mi, int* __restrict__ ws_cmask,
    float* __restrict__ out_filt) {
  int tid = threadIdx.x;
  // alpha kernels
  for (int idx = tid; idx < SUB * TNO; idx += 256) {
    int s = idx / TNO;
    float tf = (float)(idx % TNO);
    float te  = fmaxf(tf - expf(De[s]), 0.f);
    float tte = te / expf(TauE[s]);
    float ekv = tte * expf(-tte) * expf(We[s]);
    float ti_ = fmaxf(tf - expf(Di[s]), 0.f);
    float tti = ti_ / expf(TauI[s]);
    float ikv = -(tti * expf(-tti) * expf(Wi[s]));
    ws_ek[idx] = ekv;
    ws_ik[idx] = ikv;
    out_filt[idx] = ekv;            // rows 0..15
    out_filt[3200 + idx] = ikv;     // rows 16..31
  }
  // hist kernel
  for (int t = tid; t < TNO; t += 256) {
    float h = 0.f;
    for (int b = 0; b < 16; ++b) h = fmaf(Whist[b], cosb[b * TNO + t], h);
    ws_hist[t] = h;
    out_filt[6400 + t] = h;         // row 32 (unflipped)
  }
  // synapse->subunit maps (columns are one-hot in the reference setup)
  for (int e = tid; e < E_NO; e += 256) {
    int m = 0; float w = 0.f;
    for (int s = 0; s < SUB; ++s) {
      float v = Ce[s * E_NO + e];
      if (w == 0.f && v != 0.f) { m = s; w = v; }
    }
    ws_me[e] = m; ws_we[e] = w;
  }
  for (int e = tid; e < I_NO; e += 256) {
    int m = 0; float w = 0.f;
    for (int s = 0; s < SUB; ++s) {
      float v = Ci[s * I_NO + e];
      if (w == 0.f && v != 0.f) { m = s; w = v; }
    }
    ws_mi[e] = m; ws_wi[e] = w;
  }
  if (tid < SUB) {
    ws_ewsub[tid] = expf(Wsub[tid]);
    int msk = 0;
    for (int j = 0; j < SUB; ++j)
      if (Cden[tid * SUB + j] == 1) msk |= (1 << j);
    ws_cmask[tid] = msk;
  }
}

// ---------------------------------------------------------------------------
// K2: synapse aggregation S_e@C_e^T, S_i@C_i^T -> synE/synI [20000][16].
// Deterministic: per-lane LDS bins + fixed-order sequential reduction.
// ---------------------------------------------------------------------------
__global__ __launch_bounds__(256) void k_agg(
    const float4* __restrict__ Se4, const float4* __restrict__ Si4,
    const int* __restrict__ me, const float* __restrict__ we,
    const int* __restrict__ mi, const float* __restrict__ wi,
    float* __restrict__ synE, float* __restrict__ synI) {
  __shared__ float bins[4][64][33];   // [wave][lane][32 bins], stride 33 (2-way = free)
  int tid = threadIdx.x, wid = tid >> 6, l = tid & 63;
  int gw = blockIdx.x * 4 + wid;      // 0..4999
  for (int r = 0; r < 4; ++r) {
    int t = gw * 4 + r;               // 0..19999
#pragma unroll
    for (int s = 0; s < 32; ++s) bins[wid][l][s] = 0.f;
    // E synapses: 500 float4 per row
    for (int i = 0; i < 8; ++i) {
      int idx = i * 64 + l;
      if (idx < 500) {
        float4 v = Se4[(size_t)t * 500 + idx];
        int e0 = idx * 4;
        if (v.x != 0.f) bins[wid][l][me[e0 + 0]] += v.x * we[e0 + 0];
        if (v.y != 0.f) bins[wid][l][me[e0 + 1]] += v.y * we[e0 + 1];
        if (v.z != 0.f) bins[wid][l][me[e0 + 2]] += v.z * we[e0 + 2];
        if (v.w != 0.f) bins[wid][l][me[e0 + 3]] += v.w * we[e0 + 3];
      }
    }
    // I synapses: 125 float4 per row -> bins 16..31
    for (int i = 0; i < 2; ++i) {
      int idx = i * 64 + l;
      if (idx < 125) {
        float4 v = Si4[(size_t)t * 125 + idx];
        int e0 = idx * 4;
        if (v.x != 0.f) bins[wid][l][16 + mi[e0 + 0]] += v.x * wi[e0 + 0];
        if (v.y != 0.f) bins[wid][l][16 + mi[e0 + 1]] += v.y * wi[e0 + 1];
        if (v.z != 0.f) bins[wid][l][16 + mi[e0 + 2]] += v.z * wi[e0 + 2];
        if (v.w != 0.f) bins[wid][l][16 + mi[e0 + 3]] += v.w * wi[e0 + 3];
      }
    }
    __syncthreads();
    if (l < 32) {
      float a = 0.f;
      for (int k = 0; k < 64; ++k) a += bins[wid][k][l];   // fixed order
      if (l < 16) synE[(size_t)t * 16 + l] = a;
      else        synI[(size_t)t * 16 + (l - 16)] = a;
    }
    __syncthreads();
  }
}

// ---------------------------------------------------------------------------
// K3: causal filtering (strictly causal, 1-step delay) + dendritic tree
// -> negd[t] = -drive[t].
// ---------------------------------------------------------------------------
__global__ __launch_bounds__(64) void k_filt(
    const float* __restrict__ synE, const float* __restrict__ synI,
    const float* __restrict__ ek_ws, const float* __restrict__ ik_ws,
    const float* __restrict__ theta, const float* __restrict__ ewsub,
    const int* __restrict__ cmask,
    float* __restrict__ negd) {
  __shared__ float sE[264 * 17];     // rows t0-200 .. t0+63, stride 17 (conflict-free)
  __shared__ float sI[264 * 17];
  __shared__ float ekl[TNO * 16];    // [j][s]
  __shared__ float ikl[TNO * 16];
  int l = threadIdx.x;
  int t0 = blockIdx.x * 64;
  for (int idx = l; idx < 264 * 16; idx += 64) {
    int row = idx >> 4, s = idx & 15;
    int g = t0 - 200 + row;
    bool ok = (g >= 0) && (g < T_DATA);
    sE[row * 17 + s] = ok ? synE[(size_t)g * 16 + s] : 0.f;
    sI[row * 17 + s] = ok ? synI[(size_t)g * 16 + s] : 0.f;
  }
  for (int idx = l; idx < SUB * TNO; idx += 64) {
    int s = idx / TNO, j = idx % TNO;
    ekl[j * 16 + s] = ek_ws[idx];
    ikl[j * 16 + s] = ik_ws[idx];
  }
  __syncthreads();
  int t = t0 + l;
  float acc[16];
#pragma unroll
  for (int s = 0; s < 16; ++s) acc[s] = 0.f;
  // out[t] = sum_j kern[j] * syn[t-1-j]; LDS row (t-1-j) - (t0-200) = l + 199 - j
  for (int j = 0; j < TNO; ++j) {
    int base = (l + 199 - j) * 17;
    int kb = j * 16;
#pragma unroll
    for (int s = 0; s < 16; ++s)
      acc[s] = fmaf(ekl[kb + s], sE[base + s], fmaf(ikl[kb + s], sI[base + s], acc[s]));
  }
  // dendritic tree, leaf-to-root (static 16x16 unroll keeps val[] in registers)
  float th[16], ew[16]; int cm[16];
#pragma unroll
  for (int s = 0; s < 16; ++s) { th[s] = theta[s]; ew[s] = ewsub[s]; cm[s] = cmask[s]; }
  float val[16];
#pragma unroll
  for (int s = 0; s < 16; ++s) val[s] = 0.f;
#pragma unroll
  for (int sidx = 15; sidx >= 1; --sidx) {
    float sum = acc[sidx] + th[sidx];
#pragma unroll
    for (int j = 0; j < 16; ++j)
      if ((cm[sidx] >> j) & 1) sum += val[j] * ew[j];
    val[sidx] = tanhf(sum);
  }
  float drive = acc[0] + th[0];
#pragma unroll
  for (int j = 0; j < 16; ++j)
    if ((cm[0] >> j) & 1) drive += val[j] * ew[j];
  if (t < T_DATA) negd[t] = -drive;
}

// ---------------------------------------------------------------------------
// K4: sequential spike scan. 1 workgroup, 4 waves.
// wave0: lane l owns x[t0+l]; per-step ballot broadcasts the decision bit.
//   History values hpad[l .. l+127] are block-invariant -> preloaded ONCE
//   into 128 VGPRs (hreg). The sequential chain is then pure VALU/SALU:
//   v_cmp -> ballot -> s_shift -> v_cvt -> v_fma (~20 cyc/step), no LDS
//   latency in the loop-carried dependence.
// waves1-3: deep feedback m>=65 for block n+1 from spikes <= block n-1,
//   computed during block n (double-buffered, 1 barrier/block).
// ---------------------------------------------------------------------------
__global__ __launch_bounds__(256) void k_scan(
    const float* __restrict__ hist, const float* __restrict__ negd,
    float* __restrict__ out_spk) {
  __shared__ float hpad[328];        // [0..63]=0, [64..263]=h[0..199], [264..327]=0
  __shared__ float spkf[512];        // spike ring (float 0/1)
  __shared__ float deepb[2][3][64];  // parity double-buffered deep partials
  int tid = threadIdx.x, wid = tid >> 6, l = tid & 63;
  for (int i = tid; i < 328; i += 256) hpad[i] = (i >= 64 && i < 264) ? hist[i - 64] : 0.f;
  for (int i = tid; i < 512; i += 256) spkf[i] = 0.f;
  for (int i = tid; i < 2 * 3 * 64; i += 256) (&deepb[0][0][0])[i] = 0.f;
  __syncthreads();

  // Block-invariant history registers for wave0:
  //   chain    step i adds hpad[63 + l - i] = hreg[63 - i]
  //   boundary tap  i adds hpad[127 + l - i] = hreg[127 - i]
  float hreg[128];
  if (wid == 0) {
#pragma unroll
    for (int j = 0; j < 128; ++j) hreg[j] = hpad[l + j];   // static offsets -> VGPRs
  }

  unsigned long long mask_prev = 0ull;
  float ndv = (wid == 0) ? negd[l] : 0.f;
  int k0 = (wid == 1) ? 0 : (wid == 2) ? 46 : 91;
  int k1 = (wid == 1) ? 46 : (wid == 2) ? 91 : 136;

  for (int n = 0; n < NBLK; ++n) {
    int t0 = n * 64;
    if (wid == 0) {
      // prefetch next block's -drive (consumed next iteration)
      int tn = t0 + 64 + l;
      float ndnext = (tn < T_DATA) ? negd[tn] : INFINITY;
      int par = n & 1;
      float X = deepb[par][0][l] + deepb[par][1][l] + deepb[par][2][l];
      // previous-block spikes: m = 64+l-i in [1,127] — pure register math
      {
        float a0 = 0.f, a1 = 0.f, a2 = 0.f, a3 = 0.f;
#pragma unroll
        for (int i = 0; i < 64; i += 4) {
          a0 = fmaf((float)((mask_prev >> (i + 0)) & 1ull), hreg[127 - (i + 0)], a0);
          a1 = fmaf((float)((mask_prev >> (i + 1)) & 1ull), hreg[127 - (i + 1)], a1);
          a2 = fmaf((float)((mask_prev >> (i + 2)) & 1ull), hreg[127 - (i + 2)], a2);
          a3 = fmaf((float)((mask_prev >> (i + 3)) & 1ull), hreg[127 - (i + 3)], a3);
        }
        X += (a0 + a1) + (a2 + a3);
      }
      // sequential chain over 64 steps — no LDS in the dependence
      unsigned long long msk = 0ull;
#pragma unroll
      for (int i = 0; i < 64; ++i) {
        unsigned long long bm = __ballot(X > ndv);       // bit i = step-i decision
        float spf = (float)((bm >> i) & 1ull);
        X = fmaf(spf, hreg[63 - i], X);                  // h[l-i-1]; zero for l<=i
        msk |= (bm & (1ull << i));
      }
      // publish
      float myspk = (float)((msk >> l) & 1ull);
      int t = t0 + l;
      if (t < T_DATA) out_spk[t] = myspk;
      spkf[t & 511] = myspk;
      mask_prev = msk;
      ndv = ndnext;
    } else {
      // deep feedback for block n+1: spikes u = t0-1-k (k in [0,136)), m = 65+l+k
      float acc = 0.f;
      for (int k = k0; k < k1; ++k) {
        float sp = spkf[(t0 - 1 - k) & 511];
        acc = fmaf(sp, hpad[128 + l + k], acc);          // zero-clamped for m > 200
      }
      deepb[(n + 1) & 1][wid - 1][l] = acc;
    }
    __syncthreads();
  }
}

// ---------------------------------------------------------------------------
extern "C" void kernel_launch(void* const* d_in, const int* in_sizes, int n_in,
                              void* d_out, int out_size, void* d_ws, size_t ws_size,
                              hipStream_t stream) {
  const float* S_e      = (const float*)d_in[0];
  const float* S_i      = (const float*)d_in[1];
  const int*   C_den    = (const int*)d_in[2];
  const float* C_syn_e  = (const float*)d_in[3];
  const float* C_syn_i  = (const float*)d_in[4];
  const float* cos_b    = (const float*)d_in[5];
  const float* Tau_e    = (const float*)d_in[6];
  const float* Tau_i    = (const float*)d_in[7];
  const float* W_e      = (const float*)d_in[8];
  const float* W_i      = (const float*)d_in[9];
  const float* D_e      = (const float*)d_in[10];
  const float* D_i      = (const float*)d_in[11];
  const float* W_sub    = (const float*)d_in[12];
  const float* W_hist   = (const float*)d_in[13];
  const float* Theta    = (const float*)d_in[14];
  float* out = (float*)d_out;

  float* wsf      = (float*)d_ws;
  float* ws_ek    = wsf;
  float* ws_ik    = wsf + 3200;
  float* ws_hist  = wsf + 6400;
  float* ws_ewsub = wsf + 6600;
  float* ws_we    = wsf + 6616;
  float* ws_wi    = wsf + 8616;
  float* synE     = wsf + 16384;
  float* synI     = wsf + 336384;
  float* negd     = wsf + 656384;
  int*   ws_me    = (int*)(wsf + 676384);
  int*   ws_mi    = (int*)(wsf + 678384);
  int*   ws_cmask = (int*)(wsf + 678884);

  k_prep<<<dim3(1), dim3(256), 0, stream>>>(
      C_syn_e, C_syn_i, cos_b, Tau_e, Tau_i, W_e, W_i, D_e, D_i, W_sub, W_hist,
      C_den, ws_ek, ws_ik, ws_hist, ws_ewsub, ws_we, ws_wi, ws_me, ws_mi,
      ws_cmask, out + T_DATA);

  k_agg<<<dim3(1250), dim3(256), 0, stream>>>(
      (const float4*)S_e, (const float4*)S_i, ws_me, ws_we, ws_mi, ws_wi,
      synE, synI);

  k_filt<<<dim3(NBLK), dim3(64), 0, stream>>>(
      synE, synI, ws_ek, ws_ik, Theta, ws_ewsub, ws_cmask, negd);

  k_scan<<<dim3(1), dim3(256), 0, stream>>>(ws_hist, negd, out);
}

// Round 3
// 940.498 us; speedup vs baseline: 1.1479x; 1.0005x over previous
//
#include <hip/hip_runtime.h>
#include <math.h>
#include <stdint.h>

#define T_DATA 20000
#define E_NO   2000
#define I_NO   500
#define SUB    16
#define TNO    200
#define NBLK   313   // ceil(20000/64)

// ---------------- workspace layout (float offsets) ----------------
// 0       ek[3200]   (s*200+t)
// 3200    ik[3200]
// 6400    hist[200]
// 6600    ewsub[16]
// 6616    we[2000]
// 8616    wi[500]
// 16384   synE[20000*16]
// 336384  synI[20000*16]
// 656384  negd[20000]
// 676384  me[2000] (int)
// 678384  mi[500]  (int)
// 678884  cmask[16](int)

// ---------------------------------------------------------------------------
// K1: per-subunit kernels, hist kernel, synapse->subunit maps, tree masks.
// Also writes out_filters rows (e_kern 0..15, i_kern 16..31, hist 32).
// ---------------------------------------------------------------------------
__global__ __launch_bounds__(256) void k_prep(
    const float* __restrict__ Ce, const float* __restrict__ Ci,
    const float* __restrict__ cosb,
    const float* __restrict__ TauE, const float* __restrict__ TauI,
    const float* __restrict__ We,  const float* __restrict__ Wi,
    const float* __restrict__ De,  const float* __restrict__ Di,
    const float* __restrict__ Wsub, const float* __restrict__ Whist,
    const int* __restrict__ Cden,
    float* __restrict__ ws_ek, float* __restrict__ ws_ik,
    float* __restrict__ ws_hist, float* __restrict__ ws_ewsub,
    float* __restrict__ ws_we, float* __restrict__ ws_wi,
    int* __restrict__ ws_me, int* __restrict__ ws_mi, int* __restrict__ ws_cmask,
    float* __restrict__ out_filt) {
  int tid = threadIdx.x;
  // alpha kernels
  for (int idx = tid; idx < SUB * TNO; idx += 256) {
    int s = idx / TNO;
    float tf = (float)(idx % TNO);
    float te  = fmaxf(tf - expf(De[s]), 0.f);
    float tte = te / expf(TauE[s]);
    float ekv = tte * expf(-tte) * expf(We[s]);
    float ti_ = fmaxf(tf - expf(Di[s]), 0.f);
    float tti = ti_ / expf(TauI[s]);
    float ikv = -(tti * expf(-tti) * expf(Wi[s]));
    ws_ek[idx] = ekv;
    ws_ik[idx] = ikv;
    out_filt[idx] = ekv;            // rows 0..15
    out_filt[3200 + idx] = ikv;     // rows 16..31
  }
  // hist kernel
  for (int t = tid; t < TNO; t += 256) {
    float h = 0.f;
    for (int b = 0; b < 16; ++b) h = fmaf(Whist[b], cosb[b * TNO + t], h);
    ws_hist[t] = h;
    out_filt[6400 + t] = h;         // row 32 (unflipped)
  }
  // synapse->subunit maps (columns are one-hot in the reference setup)
  for (int e = tid; e < E_NO; e += 256) {
    int m = 0; float w = 0.f;
    for (int s = 0; s < SUB; ++s) {
      float v = Ce[s * E_NO + e];
      if (w == 0.f && v != 0.f) { m = s; w = v; }
    }
    ws_me[e] = m; ws_we[e] = w;
  }
  for (int e = tid; e < I_NO; e += 256) {
    int m = 0; float w = 0.f;
    for (int s = 0; s < SUB; ++s) {
      float v = Ci[s * I_NO + e];
      if (w == 0.f && v != 0.f) { m = s; w = v; }
    }
    ws_mi[e] = m; ws_wi[e] = w;
  }
  if (tid < SUB) {
    ws_ewsub[tid] = expf(Wsub[tid]);
    int msk = 0;
    for (int j = 0; j < SUB; ++j)
      if (Cden[tid * SUB + j] == 1) msk |= (1 << j);
    ws_cmask[tid] = msk;
  }
}

// ---------------------------------------------------------------------------
// K2: synapse aggregation S_e@C_e^T, S_i@C_i^T -> synE/synI [20000][16].
// Deterministic: per-lane LDS bins + fixed-order sequential reduction.
// ---------------------------------------------------------------------------
__global__ __launch_bounds__(256) void k_agg(
    const float4* __restrict__ Se4, const float4* __restrict__ Si4,
    const int* __restrict__ me, const float* __restrict__ we,
    const int* __restrict__ mi, const float* __restrict__ wi,
    float* __restrict__ synE, float* __restrict__ synI) {
  __shared__ float bins[4][64][33];   // [wave][lane][32 bins], stride 33 (2-way = free)
  int tid = threadIdx.x, wid = tid >> 6, l = tid & 63;
  int gw = blockIdx.x * 4 + wid;      // 0..4999
  for (int r = 0; r < 4; ++r) {
    int t = gw * 4 + r;               // 0..19999
#pragma unroll
    for (int s = 0; s < 32; ++s) bins[wid][l][s] = 0.f;
    // E synapses: 500 float4 per row
    for (int i = 0; i < 8; ++i) {
      int idx = i * 64 + l;
      if (idx < 500) {
        float4 v = Se4[(size_t)t * 500 + idx];
        int e0 = idx * 4;
        if (v.x != 0.f) bins[wid][l][me[e0 + 0]] += v.x * we[e0 + 0];
        if (v.y != 0.f) bins[wid][l][me[e0 + 1]] += v.y * we[e0 + 1];
        if (v.z != 0.f) bins[wid][l][me[e0 + 2]] += v.z * we[e0 + 2];
        if (v.w != 0.f) bins[wid][l][me[e0 + 3]] += v.w * we[e0 + 3];
      }
    }
    // I synapses: 125 float4 per row -> bins 16..31
    for (int i = 0; i < 2; ++i) {
      int idx = i * 64 + l;
      if (idx < 125) {
        float4 v = Si4[(size_t)t * 125 + idx];
        int e0 = idx * 4;
        if (v.x != 0.f) bins[wid][l][16 + mi[e0 + 0]] += v.x * wi[e0 + 0];
        if (v.y != 0.f) bins[wid][l][16 + mi[e0 + 1]] += v.y * wi[e0 + 1];
        if (v.z != 0.f) bins[wid][l][16 + mi[e0 + 2]] += v.z * wi[e0 + 2];
        if (v.w != 0.f) bins[wid][l][16 + mi[e0 + 3]] += v.w * wi[e0 + 3];
      }
    }
    __syncthreads();
    if (l < 32) {
      float a = 0.f;
      for (int k = 0; k < 64; ++k) a += bins[wid][k][l];   // fixed order
      if (l < 16) synE[(size_t)t * 16 + l] = a;
      else        synI[(size_t)t * 16 + (l - 16)] = a;
    }
    __syncthreads();
  }
}

// ---------------------------------------------------------------------------
// K3: causal filtering (strictly causal, 1-step delay) + dendritic tree
// -> negd[t] = -drive[t].
// ---------------------------------------------------------------------------
__global__ __launch_bounds__(64) void k_filt(
    const float* __restrict__ synE, const float* __restrict__ synI,
    const float* __restrict__ ek_ws, const float* __restrict__ ik_ws,
    const float* __restrict__ theta, const float* __restrict__ ewsub,
    const int* __restrict__ cmask,
    float* __restrict__ negd) {
  __shared__ float sE[264 * 17];     // rows t0-200 .. t0+63, stride 17 (conflict-free)
  __shared__ float sI[264 * 17];
  __shared__ float ekl[TNO * 16];    // [j][s]
  __shared__ float ikl[TNO * 16];
  int l = threadIdx.x;
  int t0 = blockIdx.x * 64;
  for (int idx = l; idx < 264 * 16; idx += 64) {
    int row = idx >> 4, s = idx & 15;
    int g = t0 - 200 + row;
    bool ok = (g >= 0) && (g < T_DATA);
    sE[row * 17 + s] = ok ? synE[(size_t)g * 16 + s] : 0.f;
    sI[row * 17 + s] = ok ? synI[(size_t)g * 16 + s] : 0.f;
  }
  for (int idx = l; idx < SUB * TNO; idx += 64) {
    int s = idx / TNO, j = idx % TNO;
    ekl[j * 16 + s] = ek_ws[idx];
    ikl[j * 16 + s] = ik_ws[idx];
  }
  __syncthreads();
  int t = t0 + l;
  float acc[16];
#pragma unroll
  for (int s = 0; s < 16; ++s) acc[s] = 0.f;
  // out[t] = sum_j kern[j] * syn[t-1-j]; LDS row (t-1-j) - (t0-200) = l + 199 - j
  for (int j = 0; j < TNO; ++j) {
    int base = (l + 199 - j) * 17;
    int kb = j * 16;
#pragma unroll
    for (int s = 0; s < 16; ++s)
      acc[s] = fmaf(ekl[kb + s], sE[base + s], fmaf(ikl[kb + s], sI[base + s], acc[s]));
  }
  // dendritic tree, leaf-to-root (static 16x16 unroll keeps val[] in registers)
  float th[16], ew[16]; int cm[16];
#pragma unroll
  for (int s = 0; s < 16; ++s) { th[s] = theta[s]; ew[s] = ewsub[s]; cm[s] = cmask[s]; }
  float val[16];
#pragma unroll
  for (int s = 0; s < 16; ++s) val[s] = 0.f;
#pragma unroll
  for (int sidx = 15; sidx >= 1; --sidx) {
    float sum = acc[sidx] + th[sidx];
#pragma unroll
    for (int j = 0; j < 16; ++j)
      if ((cm[sidx] >> j) & 1) sum += val[j] * ew[j];
    val[sidx] = tanhf(sum);
  }
  float drive = acc[0] + th[0];
#pragma unroll
  for (int j = 0; j < 16; ++j)
    if ((cm[0] >> j) & 1) drive += val[j] * ew[j];
  if (t < T_DATA) negd[t] = -drive;
}

// ---------------------------------------------------------------------------
// K4: sequential spike scan. 1 workgroup, 4 waves (one per SIMD).
// __launch_bounds__(256, 1): min 1 wave/EU -> VGPR budget 512/wave, so the
// 128-value block-invariant history table stays in VGPRs (round-2's VGPR=84
// showed the default heuristic targeted 6 waves/EU and spilled it).
// wave0: lane l owns x[t0+l]; per-step ballot broadcasts the decision bit.
// waves1-3: deep feedback m>=65 for block n+1, double-buffered.
// ---------------------------------------------------------------------------
__global__ __launch_bounds__(256, 1) void k_scan(
    const float* __restrict__ hist, const float* __restrict__ negd,
    float* __restrict__ out_spk) {
  __shared__ float hpad[328];        // [0..63]=0, [64..263]=h[0..199], [264..327]=0
  __shared__ float spkf[512];        // spike ring (float 0/1)
  __shared__ float deepb[2][3][64];  // parity double-buffered deep partials
  int tid = threadIdx.x, wid = tid >> 6, l = tid & 63;
  for (int i = tid; i < 328; i += 256) hpad[i] = (i >= 64 && i < 264) ? hist[i - 64] : 0.f;
  for (int i = tid; i < 512; i += 256) spkf[i] = 0.f;
  for (int i = tid; i < 2 * 3 * 64; i += 256) (&deepb[0][0][0])[i] = 0.f;
  __syncthreads();

  // Block-invariant history registers for wave0:
  //   chain    step i adds hpad[63 + l - i] = hreg[63 - i]
  //   boundary tap  i adds hpad[127 + l - i] = hreg[127 - i]
  float hreg[128];
  if (wid == 0) {
#pragma unroll
    for (int j = 0; j < 128; ++j) hreg[j] = hpad[l + j];   // static offsets -> VGPRs
  }

  unsigned long long mask_prev = 0ull;
  float ndv = (wid == 0) ? negd[l] : 0.f;
  int k0 = (wid == 1) ? 0 : (wid == 2) ? 46 : 91;
  int k1 = (wid == 1) ? 46 : (wid == 2) ? 91 : 136;

  for (int n = 0; n < NBLK; ++n) {
    int t0 = n * 64;
    if (wid == 0) {
      // prefetch next block's -drive (consumed next iteration)
      int tn = t0 + 64 + l;
      float ndnext = (tn < T_DATA) ? negd[tn] : INFINITY;
      int par = n & 1;
      float X = deepb[par][0][l] + deepb[par][1][l] + deepb[par][2][l];
      // previous-block spikes: m = 64+l-i in [1,127] — pure register math
      {
        float a0 = 0.f, a1 = 0.f, a2 = 0.f, a3 = 0.f;
#pragma unroll
        for (int i = 0; i < 64; i += 4) {
          a0 = fmaf((float)((mask_prev >> (i + 0)) & 1ull), hreg[127 - (i + 0)], a0);
          a1 = fmaf((float)((mask_prev >> (i + 1)) & 1ull), hreg[127 - (i + 1)], a1);
          a2 = fmaf((float)((mask_prev >> (i + 2)) & 1ull), hreg[127 - (i + 2)], a2);
          a3 = fmaf((float)((mask_prev >> (i + 3)) & 1ull), hreg[127 - (i + 3)], a3);
        }
        X += (a0 + a1) + (a2 + a3);
      }
      // sequential chain over 64 steps — pure VALU/SALU dependence
      unsigned long long msk = 0ull;
#pragma unroll
      for (int i = 0; i < 64; ++i) {
        unsigned long long bm = __ballot(X > ndv);       // bit i = step-i decision
        float spf = (float)((bm >> i) & 1ull);
        X = fmaf(spf, hreg[63 - i], X);                  // h[l-i-1]; zero for l<=i
        msk |= (bm & (1ull << i));
      }
      // publish
      float myspk = (float)((msk >> l) & 1ull);
      int t = t0 + l;
      if (t < T_DATA) out_spk[t] = myspk;
      spkf[t & 511] = myspk;
      mask_prev = msk;
      ndv = ndnext;
    } else {
      // deep feedback for block n+1: spikes u = t0-1-k (k in [0,136)), m = 65+l+k
      float acc = 0.f;
      for (int k = k0; k < k1; ++k) {
        float sp = spkf[(t0 - 1 - k) & 511];
        acc = fmaf(sp, hpad[128 + l + k], acc);          // zero-clamped for m > 200
      }
      deepb[(n + 1) & 1][wid - 1][l] = acc;
    }
    __syncthreads();
  }
}

// ---------------------------------------------------------------------------
extern "C" void kernel_launch(void* const* d_in, const int* in_sizes, int n_in,
                              void* d_out, int out_size, void* d_ws, size_t ws_size,
                              hipStream_t stream) {
  const float* S_e      = (const float*)d_in[0];
  const float* S_i      = (const float*)d_in[1];
  const int*   C_den    = (const int*)d_in[2];
  const float* C_syn_e  = (const float*)d_in[3];
  const float* C_syn_i  = (const float*)d_in[4];
  const float* cos_b    = (const float*)d_in[5];
  const float* Tau_e    = (const float*)d_in[6];
  const float* Tau_i    = (const float*)d_in[7];
  const float* W_e      = (const float*)d_in[8];
  const float* W_i      = (const float*)d_in[9];
  const float* D_e      = (const float*)d_in[10];
  const float* D_i      = (const float*)d_in[11];
  const float* W_sub    = (const float*)d_in[12];
  const float* W_hist   = (const float*)d_in[13];
  const float* Theta    = (const float*)d_in[14];
  float* out = (float*)d_out;

  float* wsf      = (float*)d_ws;
  float* ws_ek    = wsf;
  float* ws_ik    = wsf + 3200;
  float* ws_hist  = wsf + 6400;
  float* ws_ewsub = wsf + 6600;
  float* ws_we    = wsf + 6616;
  float* ws_wi    = wsf + 8616;
  float* synE     = wsf + 16384;
  float* synI     = wsf + 336384;
  float* negd     = wsf + 656384;
  int*   ws_me    = (int*)(wsf + 676384);
  int*   ws_mi    = (int*)(wsf + 678384);
  int*   ws_cmask = (int*)(wsf + 678884);

  k_prep<<<dim3(1), dim3(256), 0, stream>>>(
      C_syn_e, C_syn_i, cos_b, Tau_e, Tau_i, W_e, W_i, D_e, D_i, W_sub, W_hist,
      C_den, ws_ek, ws_ik, ws_hist, ws_ewsub, ws_we, ws_wi, ws_me, ws_mi,
      ws_cmask, out + T_DATA);

  k_agg<<<dim3(1250), dim3(256), 0, stream>>>(
      (const float4*)S_e, (const float4*)S_i, ws_me, ws_we, ws_mi, ws_wi,
      synE, synI);

  k_filt<<<dim3(NBLK), dim3(64), 0, stream>>>(
      synE, synI, ws_ek, ws_ik, Theta, ws_ewsub, ws_cmask, negd);

  k_scan<<<dim3(1), dim3(256), 0, stream>>>(ws_hist, negd, out);
}

// Round 4
// 935.626 us; speedup vs baseline: 1.1539x; 1.0052x over previous
//
#include <hip/hip_runtime.h>
#include <math.h>
#include <stdint.h>

#define T_DATA 20000
#define E_NO   2000
#define I_NO   500
#define SUB    16
#define TNO    200
#define NBLK   313   // ceil(20000/64)

// ---------------- workspace layout (float offsets) ----------------
// 0       ek[3200]   (s*200+t)
// 3200    ik[3200]
// 6400    hist[200]
// 6600    ewsub[16]
// 6616    we[2000]
// 8616    wi[500]
// 16384   synE[20000*16]
// 336384  synI[20000*16]
// 656384  negd[20000]
// 676384  me[2000] (int)
// 678384  mi[500]  (int)
// 678884  cmask[16](int)

// ---------------------------------------------------------------------------
// K1: per-subunit kernels, hist kernel, synapse->subunit maps, tree masks.
// ---------------------------------------------------------------------------
__global__ __launch_bounds__(256) void k_prep(
    const float* __restrict__ Ce, const float* __restrict__ Ci,
    const float* __restrict__ cosb,
    const float* __restrict__ TauE, const float* __restrict__ TauI,
    const float* __restrict__ We,  const float* __restrict__ Wi,
    const float* __restrict__ De,  const float* __restrict__ Di,
    const float* __restrict__ Wsub, const float* __restrict__ Whist,
    const int* __restrict__ Cden,
    float* __restrict__ ws_ek, float* __restrict__ ws_ik,
    float* __restrict__ ws_hist, float* __restrict__ ws_ewsub,
    float* __restrict__ ws_we, float* __restrict__ ws_wi,
    int* __restrict__ ws_me, int* __restrict__ ws_mi, int* __restrict__ ws_cmask,
    float* __restrict__ out_filt) {
  int tid = threadIdx.x;
  for (int idx = tid; idx < SUB * TNO; idx += 256) {
    int s = idx / TNO;
    float tf = (float)(idx % TNO);
    float te  = fmaxf(tf - expf(De[s]), 0.f);
    float tte = te / expf(TauE[s]);
    float ekv = tte * expf(-tte) * expf(We[s]);
    float ti_ = fmaxf(tf - expf(Di[s]), 0.f);
    float tti = ti_ / expf(TauI[s]);
    float ikv = -(tti * expf(-tti) * expf(Wi[s]));
    ws_ek[idx] = ekv;
    ws_ik[idx] = ikv;
    out_filt[idx] = ekv;            // rows 0..15
    out_filt[3200 + idx] = ikv;     // rows 16..31
  }
  for (int t = tid; t < TNO; t += 256) {
    float h = 0.f;
    for (int b = 0; b < 16; ++b) h = fmaf(Whist[b], cosb[b * TNO + t], h);
    ws_hist[t] = h;
    out_filt[6400 + t] = h;         // row 32 (unflipped)
  }
  for (int e = tid; e < E_NO; e += 256) {
    int m = 0; float w = 0.f;
    for (int s = 0; s < SUB; ++s) {
      float v = Ce[s * E_NO + e];
      if (w == 0.f && v != 0.f) { m = s; w = v; }
    }
    ws_me[e] = m; ws_we[e] = w;
  }
  for (int e = tid; e < I_NO; e += 256) {
    int m = 0; float w = 0.f;
    for (int s = 0; s < SUB; ++s) {
      float v = Ci[s * I_NO + e];
      if (w == 0.f && v != 0.f) { m = s; w = v; }
    }
    ws_mi[e] = m; ws_wi[e] = w;
  }
  if (tid < SUB) {
    ws_ewsub[tid] = expf(Wsub[tid]);
    int msk = 0;
    for (int j = 0; j < SUB; ++j)
      if (Cden[tid * SUB + j] == 1) msk |= (1 << j);
    ws_cmask[tid] = msk;
  }
}

// ---------------------------------------------------------------------------
// K2: synapse aggregation -> synE/synI [20000][16]. Deterministic.
// ---------------------------------------------------------------------------
__global__ __launch_bounds__(256) void k_agg(
    const float4* __restrict__ Se4, const float4* __restrict__ Si4,
    const int* __restrict__ me, const float* __restrict__ we,
    const int* __restrict__ mi, const float* __restrict__ wi,
    float* __restrict__ synE, float* __restrict__ synI) {
  __shared__ float bins[4][64][33];
  int tid = threadIdx.x, wid = tid >> 6, l = tid & 63;
  int gw = blockIdx.x * 4 + wid;
  for (int r = 0; r < 4; ++r) {
    int t = gw * 4 + r;
#pragma unroll
    for (int s = 0; s < 32; ++s) bins[wid][l][s] = 0.f;
    for (int i = 0; i < 8; ++i) {
      int idx = i * 64 + l;
      if (idx < 500) {
        float4 v = Se4[(size_t)t * 500 + idx];
        int e0 = idx * 4;
        if (v.x != 0.f) bins[wid][l][me[e0 + 0]] += v.x * we[e0 + 0];
        if (v.y != 0.f) bins[wid][l][me[e0 + 1]] += v.y * we[e0 + 1];
        if (v.z != 0.f) bins[wid][l][me[e0 + 2]] += v.z * we[e0 + 2];
        if (v.w != 0.f) bins[wid][l][me[e0 + 3]] += v.w * we[e0 + 3];
      }
    }
    for (int i = 0; i < 2; ++i) {
      int idx = i * 64 + l;
      if (idx < 125) {
        float4 v = Si4[(size_t)t * 125 + idx];
        int e0 = idx * 4;
        if (v.x != 0.f) bins[wid][l][16 + mi[e0 + 0]] += v.x * wi[e0 + 0];
        if (v.y != 0.f) bins[wid][l][16 + mi[e0 + 1]] += v.y * wi[e0 + 1];
        if (v.z != 0.f) bins[wid][l][16 + mi[e0 + 2]] += v.z * wi[e0 + 2];
        if (v.w != 0.f) bins[wid][l][16 + mi[e0 + 3]] += v.w * wi[e0 + 3];
      }
    }
    __syncthreads();
    if (l < 32) {
      float a = 0.f;
      for (int k = 0; k < 64; ++k) a += bins[wid][k][l];
      if (l < 16) synE[(size_t)t * 16 + l] = a;
      else        synI[(size_t)t * 16 + (l - 16)] = a;
    }
    __syncthreads();
  }
}

// ---------------------------------------------------------------------------
// K3: causal filtering + dendritic tree -> negd[t] = -drive[t].
// ---------------------------------------------------------------------------
__global__ __launch_bounds__(64) void k_filt(
    const float* __restrict__ synE, const float* __restrict__ synI,
    const float* __restrict__ ek_ws, const float* __restrict__ ik_ws,
    const float* __restrict__ theta, const float* __restrict__ ewsub,
    const int* __restrict__ cmask,
    float* __restrict__ negd) {
  __shared__ float sE[264 * 17];
  __shared__ float sI[264 * 17];
  __shared__ float ekl[TNO * 16];
  __shared__ float ikl[TNO * 16];
  int l = threadIdx.x;
  int t0 = blockIdx.x * 64;
  for (int idx = l; idx < 264 * 16; idx += 64) {
    int row = idx >> 4, s = idx & 15;
    int g = t0 - 200 + row;
    bool ok = (g >= 0) && (g < T_DATA);
    sE[row * 17 + s] = ok ? synE[(size_t)g * 16 + s] : 0.f;
    sI[row * 17 + s] = ok ? synI[(size_t)g * 16 + s] : 0.f;
  }
  for (int idx = l; idx < SUB * TNO; idx += 64) {
    int s = idx / TNO, j = idx % TNO;
    ekl[j * 16 + s] = ek_ws[idx];
    ikl[j * 16 + s] = ik_ws[idx];
  }
  __syncthreads();
  int t = t0 + l;
  float acc[16];
#pragma unroll
  for (int s = 0; s < 16; ++s) acc[s] = 0.f;
  for (int j = 0; j < TNO; ++j) {
    int base = (l + 199 - j) * 17;
    int kb = j * 16;
#pragma unroll
    for (int s = 0; s < 16; ++s)
      acc[s] = fmaf(ekl[kb + s], sE[base + s], fmaf(ikl[kb + s], sI[base + s], acc[s]));
  }
  float th[16], ew[16]; int cm[16];
#pragma unroll
  for (int s = 0; s < 16; ++s) { th[s] = theta[s]; ew[s] = ewsub[s]; cm[s] = cmask[s]; }
  float val[16];
#pragma unroll
  for (int s = 0; s < 16; ++s) val[s] = 0.f;
#pragma unroll
  for (int sidx = 15; sidx >= 1; --sidx) {
    float sum = acc[sidx] + th[sidx];
#pragma unroll
    for (int j = 0; j < 16; ++j)
      if ((cm[sidx] >> j) & 1) sum += val[j] * ew[j];
    val[sidx] = tanhf(sum);
  }
  float drive = acc[0] + th[0];
#pragma unroll
  for (int j = 0; j < 16; ++j)
    if ((cm[0] >> j) & 1) drive += val[j] * ew[j];
  if (t < T_DATA) negd[t] = -drive;
}

// ---------------------------------------------------------------------------
// K4: sequential spike scan. 1 workgroup, 4 waves (one per SIMD).
// History table held in 128 NAMED scalar floats (h0..h127) — named scalars
// are SSA values and cannot be demoted to scratch (rounds 2-3 showed the
// hreg[128] array was never SROA-promoted: VGPR=84 both rounds).
//   chain    step i adds h(63-i)  == hpad[l+63-i]
//   boundary tap  i adds h(127-i) == hpad[l+127-i]
// ---------------------------------------------------------------------------
__global__ __launch_bounds__(256, 1) void k_scan(
    const float* __restrict__ hist, const float* __restrict__ negd,
    float* __restrict__ out_spk) {
  __shared__ float hpad[328];        // [0..63]=0, [64..263]=h[0..199], [264..327]=0
  __shared__ float spkf[512];        // spike ring (float 0/1)
  __shared__ float deepb[2][3][64];  // parity double-buffered deep partials
  int tid = threadIdx.x, wid = tid >> 6, l = tid & 63;
  for (int i = tid; i < 328; i += 256) hpad[i] = (i >= 64 && i < 264) ? hist[i - 64] : 0.f;
  for (int i = tid; i < 512; i += 256) spkf[i] = 0.f;
  for (int i = tid; i < 2 * 3 * 64; i += 256) (&deepb[0][0][0])[i] = 0.f;
  __syncthreads();

  // 128 named history registers (wave0 only; other waves leave them dead)
  float h0=0,h1=0,h2=0,h3=0,h4=0,h5=0,h6=0,h7=0,h8=0,h9=0,h10=0,h11=0,h12=0,h13=0,h14=0,h15=0,
        h16=0,h17=0,h18=0,h19=0,h20=0,h21=0,h22=0,h23=0,h24=0,h25=0,h26=0,h27=0,h28=0,h29=0,h30=0,h31=0,
        h32=0,h33=0,h34=0,h35=0,h36=0,h37=0,h38=0,h39=0,h40=0,h41=0,h42=0,h43=0,h44=0,h45=0,h46=0,h47=0,
        h48=0,h49=0,h50=0,h51=0,h52=0,h53=0,h54=0,h55=0,h56=0,h57=0,h58=0,h59=0,h60=0,h61=0,h62=0,h63=0,
        h64=0,h65=0,h66=0,h67=0,h68=0,h69=0,h70=0,h71=0,h72=0,h73=0,h74=0,h75=0,h76=0,h77=0,h78=0,h79=0,
        h80=0,h81=0,h82=0,h83=0,h84=0,h85=0,h86=0,h87=0,h88=0,h89=0,h90=0,h91=0,h92=0,h93=0,h94=0,h95=0,
        h96=0,h97=0,h98=0,h99=0,h100=0,h101=0,h102=0,h103=0,h104=0,h105=0,h106=0,h107=0,h108=0,h109=0,h110=0,h111=0,
        h112=0,h113=0,h114=0,h115=0,h116=0,h117=0,h118=0,h119=0,h120=0,h121=0,h122=0,h123=0,h124=0,h125=0,h126=0,h127=0;
  if (wid == 0) {
#define LD(j) h##j = hpad[l + j];
    LD(0)LD(1)LD(2)LD(3)LD(4)LD(5)LD(6)LD(7)LD(8)LD(9)LD(10)LD(11)LD(12)LD(13)LD(14)LD(15)
    LD(16)LD(17)LD(18)LD(19)LD(20)LD(21)LD(22)LD(23)LD(24)LD(25)LD(26)LD(27)LD(28)LD(29)LD(30)LD(31)
    LD(32)LD(33)LD(34)LD(35)LD(36)LD(37)LD(38)LD(39)LD(40)LD(41)LD(42)LD(43)LD(44)LD(45)LD(46)LD(47)
    LD(48)LD(49)LD(50)LD(51)LD(52)LD(53)LD(54)LD(55)LD(56)LD(57)LD(58)LD(59)LD(60)LD(61)LD(62)LD(63)
    LD(64)LD(65)LD(66)LD(67)LD(68)LD(69)LD(70)LD(71)LD(72)LD(73)LD(74)LD(75)LD(76)LD(77)LD(78)LD(79)
    LD(80)LD(81)LD(82)LD(83)LD(84)LD(85)LD(86)LD(87)LD(88)LD(89)LD(90)LD(91)LD(92)LD(93)LD(94)LD(95)
    LD(96)LD(97)LD(98)LD(99)LD(100)LD(101)LD(102)LD(103)LD(104)LD(105)LD(106)LD(107)LD(108)LD(109)LD(110)LD(111)
    LD(112)LD(113)LD(114)LD(115)LD(116)LD(117)LD(118)LD(119)LD(120)LD(121)LD(122)LD(123)LD(124)LD(125)LD(126)LD(127)
#undef LD
  }

  unsigned long long mask_prev = 0ull;
  float ndv = (wid == 0) ? negd[l] : 0.f;
  int k0 = (wid == 1) ? 0 : (wid == 2) ? 46 : 91;
  int k1 = (wid == 1) ? 46 : (wid == 2) ? 91 : 136;

  for (int n = 0; n < NBLK; ++n) {
    int t0 = n * 64;
    if (wid == 0) {
      int tn = t0 + 64 + l;
      float ndnext = (tn < T_DATA) ? negd[tn] : INFINITY;
      int par = n & 1;
      float X = deepb[par][0][l] + deepb[par][1][l] + deepb[par][2][l];
      // boundary conv: tap i adds h(127-i) when prev-block bit i set
      {
        float a0 = 0.f, a1 = 0.f, a2 = 0.f, a3 = 0.f;
#define BD(i, hv, acc) acc = fmaf((float)((mask_prev >> (i)) & 1ull), hv, acc);
        BD(0,h127,a0)BD(1,h126,a1)BD(2,h125,a2)BD(3,h124,a3)
        BD(4,h123,a0)BD(5,h122,a1)BD(6,h121,a2)BD(7,h120,a3)
        BD(8,h119,a0)BD(9,h118,a1)BD(10,h117,a2)BD(11,h116,a3)
        BD(12,h115,a0)BD(13,h114,a1)BD(14,h113,a2)BD(15,h112,a3)
        BD(16,h111,a0)BD(17,h110,a1)BD(18,h109,a2)BD(19,h108,a3)
        BD(20,h107,a0)BD(21,h106,a1)BD(22,h105,a2)BD(23,h104,a3)
        BD(24,h103,a0)BD(25,h102,a1)BD(26,h101,a2)BD(27,h100,a3)
        BD(28,h99,a0)BD(29,h98,a1)BD(30,h97,a2)BD(31,h96,a3)
        BD(32,h95,a0)BD(33,h94,a1)BD(34,h93,a2)BD(35,h92,a3)
        BD(36,h91,a0)BD(37,h90,a1)BD(38,h89,a2)BD(39,h88,a3)
        BD(40,h87,a0)BD(41,h86,a1)BD(42,h85,a2)BD(43,h84,a3)
        BD(44,h83,a0)BD(45,h82,a1)BD(46,h81,a2)BD(47,h80,a3)
        BD(48,h79,a0)BD(49,h78,a1)BD(50,h77,a2)BD(51,h76,a3)
        BD(52,h75,a0)BD(53,h74,a1)BD(54,h73,a2)BD(55,h72,a3)
        BD(56,h71,a0)BD(57,h70,a1)BD(58,h69,a2)BD(59,h68,a3)
        BD(60,h67,a0)BD(61,h66,a1)BD(62,h65,a2)BD(63,h64,a3)
#undef BD
        X += (a0 + a1) + (a2 + a3);
      }
      // sequential chain: step i adds h(63-i) when bit i fires
      unsigned long long msk = 0ull;
#define CH(i, hv) { unsigned long long bm = __ballot(X > ndv); \
                    X = fmaf((float)((bm >> (i)) & 1ull), hv, X); \
                    msk |= (bm & (1ull << (i))); }
      CH(0,h63)CH(1,h62)CH(2,h61)CH(3,h60)CH(4,h59)CH(5,h58)CH(6,h57)CH(7,h56)
      CH(8,h55)CH(9,h54)CH(10,h53)CH(11,h52)CH(12,h51)CH(13,h50)CH(14,h49)CH(15,h48)
      CH(16,h47)CH(17,h46)CH(18,h45)CH(19,h44)CH(20,h43)CH(21,h42)CH(22,h41)CH(23,h40)
      CH(24,h39)CH(25,h38)CH(26,h37)CH(27,h36)CH(28,h35)CH(29,h34)CH(30,h33)CH(31,h32)
      CH(32,h31)CH(33,h30)CH(34,h29)CH(35,h28)CH(36,h27)CH(37,h26)CH(38,h25)CH(39,h24)
      CH(40,h23)CH(41,h22)CH(42,h21)CH(43,h20)CH(44,h19)CH(45,h18)CH(46,h17)CH(47,h16)
      CH(48,h15)CH(49,h14)CH(50,h13)CH(51,h12)CH(52,h11)CH(53,h10)CH(54,h9)CH(55,h8)
      CH(56,h7)CH(57,h6)CH(58,h5)CH(59,h4)CH(60,h3)CH(61,h2)CH(62,h1)CH(63,h0)
#undef CH
      // publish
      float myspk = (float)((msk >> l) & 1ull);
      int t = t0 + l;
      if (t < T_DATA) out_spk[t] = myspk;
      spkf[t & 511] = myspk;
      mask_prev = msk;
      ndv = ndnext;
    } else {
      // deep feedback for block n+1: spikes u = t0-1-k (k in [0,136)), m = 65+l+k
      float acc = 0.f;
      for (int k = k0; k < k1; ++k) {
        float sp = spkf[(t0 - 1 - k) & 511];
        acc = fmaf(sp, hpad[128 + l + k], acc);          // zero-clamped for m > 200
      }
      deepb[(n + 1) & 1][wid - 1][l] = acc;
    }
    __syncthreads();
  }
}

// ---------------------------------------------------------------------------
extern "C" void kernel_launch(void* const* d_in, const int* in_sizes, int n_in,
                              void* d_out, int out_size, void* d_ws, size_t ws_size,
                              hipStream_t stream) {
  const float* S_e      = (const float*)d_in[0];
  const float* S_i      = (const float*)d_in[1];
  const int*   C_den    = (const int*)d_in[2];
  const float* C_syn_e  = (const float*)d_in[3];
  const float* C_syn_i  = (const float*)d_in[4];
  const float* cos_b    = (const float*)d_in[5];
  const float* Tau_e    = (const float*)d_in[6];
  const float* Tau_i    = (const float*)d_in[7];
  const float* W_e      = (const float*)d_in[8];
  const float* W_i      = (const float*)d_in[9];
  const float* D_e      = (const float*)d_in[10];
  const float* D_i      = (const float*)d_in[11];
  const float* W_sub    = (const float*)d_in[12];
  const float* W_hist   = (const float*)d_in[13];
  const float* Theta    = (const float*)d_in[14];
  float* out = (float*)d_out;

  float* wsf      = (float*)d_ws;
  float* ws_ek    = wsf;
  float* ws_ik    = wsf + 3200;
  float* ws_hist  = wsf + 6400;
  float* ws_ewsub = wsf + 6600;
  float* ws_we    = wsf + 6616;
  float* ws_wi    = wsf + 8616;
  float* synE     = wsf + 16384;
  float* synI     = wsf + 336384;
  float* negd     = wsf + 656384;
  int*   ws_me    = (int*)(wsf + 676384);
  int*   ws_mi    = (int*)(wsf + 678384);
  int*   ws_cmask = (int*)(wsf + 678884);

  k_prep<<<dim3(1), dim3(256), 0, stream>>>(
      C_syn_e, C_syn_i, cos_b, Tau_e, Tau_i, W_e, W_i, D_e, D_i, W_sub, W_hist,
      C_den, ws_ek, ws_ik, ws_hist, ws_ewsub, ws_we, ws_wi, ws_me, ws_mi,
      ws_cmask, out + T_DATA);

  k_agg<<<dim3(1250), dim3(256), 0, stream>>>(
      (const float4*)S_e, (const float4*)S_i, ws_me, ws_we, ws_mi, ws_wi,
      synE, synI);

  k_filt<<<dim3(NBLK), dim3(64), 0, stream>>>(
      synE, synI, ws_ek, ws_ik, Theta, ws_ewsub, ws_cmask, negd);

  k_scan<<<dim3(1), dim3(256), 0, stream>>>(ws_hist, negd, out);
}